// Round 1
// baseline (785.630 us; speedup 1.0000x reference)
//
#include <hip/hip_runtime.h>
#include <math.h>

// Problem constants
#define B_  8
#define N_  196
#define C_  12
#define D_  768
#define H_  12
#define CHD 4
#define SHD 16
#define R_  (B_*N_*C_)      // 18816 rows of x
#define NQKV 720            // 144 (channel) + 576 (spatial)

// ---------------------------------------------------------------------------
// Tiled fp32 GEMM: out[M x Nt] = A[M x K] @ W^T  (+bias), where W rows come
// from W0 (rows < split) or W1 (rows >= split). 64x64 tile, 4x4 microtile.
// M must be a multiple of 64; Nt guarded.
// ---------------------------------------------------------------------------
__global__ __launch_bounds__(256) void gemm_xWt(
    const float* __restrict__ A,
    const float* __restrict__ W0,
    const float* __restrict__ W1,
    int split,
    const float* __restrict__ bias,
    float* __restrict__ out,
    int M, int Nt, int K)
{
    __shared__ float As[16][64];
    __shared__ float Bs[16][64];

    const int tid = threadIdx.x;
    const int tx = tid & 15;        // 0..15 -> output cols
    const int ty = tid >> 4;        // 0..15 -> output rows
    const int m0 = blockIdx.x * 64;
    const int n0 = blockIdx.y * 64;

    const int lrow  = tid >> 2;          // 0..63
    const int lcol4 = (tid & 3) << 2;    // 0,4,8,12

    const float* arowptr = A + (size_t)(m0 + lrow) * K;
    const int nB = n0 + lrow;
    const float* wrow = nullptr;
    if (nB < Nt)
        wrow = (nB < split) ? (W0 + (size_t)nB * K)
                            : (W1 + (size_t)(nB - split) * K);

    float acc[4][4] = {};

    for (int kt = 0; kt < K; kt += 16) {
        float4 av = *reinterpret_cast<const float4*>(arowptr + kt + lcol4);
        float4 bv = make_float4(0.f, 0.f, 0.f, 0.f);
        if (wrow) bv = *reinterpret_cast<const float4*>(wrow + kt + lcol4);

        As[lcol4 + 0][lrow] = av.x;
        As[lcol4 + 1][lrow] = av.y;
        As[lcol4 + 2][lrow] = av.z;
        As[lcol4 + 3][lrow] = av.w;
        Bs[lcol4 + 0][lrow] = bv.x;
        Bs[lcol4 + 1][lrow] = bv.y;
        Bs[lcol4 + 2][lrow] = bv.z;
        Bs[lcol4 + 3][lrow] = bv.w;
        __syncthreads();

        #pragma unroll
        for (int k = 0; k < 16; ++k) {
            float4 a = *reinterpret_cast<const float4*>(&As[k][ty << 2]);
            float4 b = *reinterpret_cast<const float4*>(&Bs[k][tx << 2]);
            acc[0][0] += a.x * b.x; acc[0][1] += a.x * b.y; acc[0][2] += a.x * b.z; acc[0][3] += a.x * b.w;
            acc[1][0] += a.y * b.x; acc[1][1] += a.y * b.y; acc[1][2] += a.y * b.z; acc[1][3] += a.y * b.w;
            acc[2][0] += a.z * b.x; acc[2][1] += a.z * b.y; acc[2][2] += a.z * b.z; acc[2][3] += a.z * b.w;
            acc[3][0] += a.w * b.x; acc[3][1] += a.w * b.y; acc[3][2] += a.w * b.z; acc[3][3] += a.w * b.w;
        }
        __syncthreads();
    }

    #pragma unroll
    for (int i = 0; i < 4; ++i) {
        const int row = m0 + (ty << 2) + i;
        #pragma unroll
        for (int j = 0; j < 4; ++j) {
            const int col = n0 + (tx << 2) + j;
            if (col < Nt) {
                float v = acc[i][j];
                if (bias) v += bias[col];
                out[(size_t)row * Nt + col] = v;
            }
        }
    }
}

// ---------------------------------------------------------------------------
// Spatial attention: one block per (b,h,c); q,k,v are (196 x 16).
// qkv layout: [r=(b*196+n)*12+c][720], spatial cols = 144 + s*192 + h*16 + e.
// Output xs[((b*12+h)*196+n)*12 + c][16].
// ---------------------------------------------------------------------------
__global__ __launch_bounds__(256) void spatial_attn(
    const float* __restrict__ qkv,
    float* __restrict__ xs_out)
{
    const int bid = blockIdx.x;          // 8*12*12 = 1152
    const int c = bid % 12;
    const int h = (bid / 12) % 12;
    const int b = bid / 144;

    __shared__ float sQ[196][17];
    __shared__ float sK[196][17];
    __shared__ float sV[196][17];

    for (int idx = threadIdx.x; idx < N_ * 16; idx += 256) {
        const int n = idx >> 4, e = idx & 15;
        const float* base = qkv + (size_t)((b * N_ + n) * 12 + c) * NQKV + 144 + h * 16 + e;
        sQ[n][e] = base[0];
        sK[n][e] = base[192];
        sV[n][e] = base[384];
    }
    __syncthreads();

    const int n = threadIdx.x;
    if (n < N_) {
        float q[16];
        #pragma unroll
        for (int e = 0; e < 16; ++e) q[e] = sQ[n][e] * 0.25f;  // scale = shd^-0.5

        float m = -INFINITY, l = 0.f;
        float acc[16] = {};
        for (int n2 = 0; n2 < N_; ++n2) {
            float s = 0.f;
            #pragma unroll
            for (int e = 0; e < 16; ++e) s += q[e] * sK[n2][e];
            const float mn = fmaxf(m, s);
            const float corr = __expf(m - mn);   // first iter: exp(-inf) = 0
            const float p = __expf(s - mn);
            l = l * corr + p;
            #pragma unroll
            for (int e = 0; e < 16; ++e) acc[e] = acc[e] * corr + p * sV[n2][e];
            m = mn;
        }
        const float inv = 1.f / l;
        const size_t orow = ((size_t)(b * 12 + h) * N_ + n) * 12 + c;
        #pragma unroll
        for (int e = 0; e < 16; ++e) xs_out[orow * 16 + e] = acc[e] * inv;
    }
}

// ---------------------------------------------------------------------------
// Channel attention (12x4 per (b,h,n)) + outer-product combine -> y.
// y[(b*196+n)*12 + h][c*64 + i*16 + j] = xc[c][i] * xs[c][j]
// ---------------------------------------------------------------------------
__global__ __launch_bounds__(64) void chan_attn_combine(
    const float* __restrict__ qkv,
    const float* __restrict__ xs,
    float* __restrict__ y)
{
    const int bid = blockIdx.x;            // ((b*12+h)*196 + n)
    const int n = bid % N_;
    const int h = (bid / N_) % 12;
    const int b = bid / (N_ * 12);
    const int t = threadIdx.x;

    __shared__ float sQ[12][4], sK[12][4], sV[12][4], sXc[12][4];
    __shared__ float sXs[12][16];

    for (int idx = t; idx < 144; idx += 64) {
        const int c = idx / 12, rem = idx % 12, s = rem >> 2, e = rem & 3;
        const float v = qkv[(size_t)((b * N_ + n) * 12 + c) * NQKV + s * 48 + h * 4 + e];
        if (s == 0) sQ[c][e] = v;
        else if (s == 1) sK[c][e] = v;
        else sV[c][e] = v;
    }
    for (int idx = t; idx < 192; idx += 64) {
        const int c = idx >> 4, j = idx & 15;
        sXs[c][j] = xs[(size_t)(((b * 12 + h) * N_ + n) * 12 + c) * 16 + j];
    }
    __syncthreads();

    if (t < 12) {
        const int c = t;
        float s[12];
        float m = -INFINITY;
        #pragma unroll
        for (int c2 = 0; c2 < 12; ++c2) {
            float d = 0.f;
            #pragma unroll
            for (int e = 0; e < 4; ++e) d += sQ[c][e] * sK[c2][e];
            s[c2] = d * 0.5f;                 // scale = chd^-0.5
            m = fmaxf(m, s[c2]);
        }
        float l = 0.f;
        #pragma unroll
        for (int c2 = 0; c2 < 12; ++c2) { s[c2] = __expf(s[c2] - m); l += s[c2]; }
        const float inv = 1.f / l;
        #pragma unroll
        for (int i = 0; i < 4; ++i) {
            float a = 0.f;
            #pragma unroll
            for (int c2 = 0; c2 < 12; ++c2) a += s[c2] * sV[c2][i];
            sXc[c][i] = a * inv;
        }
    }
    __syncthreads();

    const size_t yrow = ((size_t)(b * N_ + n) * 12 + h) * (size_t)D_;
    #pragma unroll
    for (int k = 0; k < 12; ++k) {
        y[yrow + k * 64 + t] = sXc[k][t >> 4] * sXs[k][t & 15];
    }
}

// ---------------------------------------------------------------------------
extern "C" void kernel_launch(void* const* d_in, const int* in_sizes, int n_in,
                              void* d_out, int out_size, void* d_ws, size_t ws_size,
                              hipStream_t stream) {
    const float* x       = (const float*)d_in[0];
    const float* w_qkv_c = (const float*)d_in[1];
    const float* w_qkv_s = (const float*)d_in[2];
    const float* w_proj  = (const float*)d_in[3];
    const float* b_proj  = (const float*)d_in[4];
    float* out = (float*)d_out;

    // Workspace layout
    float* qkv = (float*)d_ws;                                  // R_ x 720
    float* xs  = qkv + (size_t)R_ * NQKV;                       // B*H*N*C x 16
    float* y   = xs + (size_t)B_ * H_ * N_ * C_ * 16;           // R_ x 768

    // 1) fused qkv GEMM: cols [0,144) = channel, [144,720) = spatial
    {
        dim3 grid(R_ / 64, (NQKV + 63) / 64);
        gemm_xWt<<<grid, 256, 0, stream>>>(x, w_qkv_c, w_qkv_s, 144, nullptr,
                                           qkv, R_, NQKV, D_);
    }
    // 2) spatial attention
    spatial_attn<<<B_ * H_ * C_, 256, 0, stream>>>(qkv, xs);
    // 3) channel attention + combine
    chan_attn_combine<<<B_ * H_ * N_, 64, 0, stream>>>(qkv, xs, y);
    // 4) projection GEMM (+bias) straight into d_out
    {
        dim3 grid(R_ / 64, D_ / 64);
        gemm_xWt<<<grid, 256, 0, stream>>>(y, w_proj, w_proj, 1 << 30, b_proj,
                                           out, R_, D_, D_);
    }
}

// Round 2
// 354.992 us; speedup vs baseline: 2.2131x; 2.2131x over previous
//
#include <hip/hip_runtime.h>
#include <math.h>

// Problem constants
#define B_  8
#define N_  196
#define C_  12
#define D_  768
#define H_  12
#define R_  (B_*N_*C_)      // 18816 rows
#define KDIM 768
#define NQKV_PAD 768        // 720 real qkv cols padded to 768

typedef unsigned short ushort_t;
typedef __attribute__((ext_vector_type(8))) short bf16x8;   // 8 bf16 = 4 VGPR
typedef __attribute__((ext_vector_type(4))) float f32x4;

__device__ inline unsigned short f2bf(float f) {
    union { float f; unsigned u; } v; v.f = f;
    unsigned r = v.u + 0x7fffu + ((v.u >> 16) & 1u);   // RNE
    return (unsigned short)(r >> 16);
}
__device__ inline float bf2f(unsigned short h) {
    union { unsigned u; float f; } v; v.u = ((unsigned)h) << 16; return v.f;
}

// ---------------------------------------------------------------------------
// fp32 -> (bf16 hi, bf16 lo) elementwise split. n must be a multiple of 4.
// ---------------------------------------------------------------------------
__global__ __launch_bounds__(256) void convert_split(
    const float* __restrict__ in, unsigned short* __restrict__ hi,
    unsigned short* __restrict__ lo, int n)
{
    int i = (blockIdx.x * 256 + threadIdx.x) * 4;
    if (i >= n) return;
    float4 v = *reinterpret_cast<const float4*>(in + i);
    ushort4 h, l;
    h.x = f2bf(v.x); l.x = f2bf(v.x - bf2f(h.x));
    h.y = f2bf(v.y); l.y = f2bf(v.y - bf2f(h.y));
    h.z = f2bf(v.z); l.z = f2bf(v.z - bf2f(h.z));
    h.w = f2bf(v.w); l.w = f2bf(v.w - bf2f(h.w));
    *reinterpret_cast<ushort4*>(hi + i) = h;
    *reinterpret_cast<ushort4*>(lo + i) = l;
}

// Pack w_qkv_c (144x768) + w_qkv_s (576x768) into padded 768x768 hi/lo.
__global__ __launch_bounds__(256) void convert_wqkv(
    const float* __restrict__ wc, const float* __restrict__ ws,
    unsigned short* __restrict__ hi, unsigned short* __restrict__ lo)
{
    int i = (blockIdx.x * 256 + threadIdx.x) * 4;   // flat elem idx, 768*768 total
    if (i >= 768 * 768) return;
    int r = i / 768, k = i % 768;
    float4 v = make_float4(0.f, 0.f, 0.f, 0.f);
    if (r < 144)      v = *reinterpret_cast<const float4*>(wc + r * 768 + k);
    else if (r < 720) v = *reinterpret_cast<const float4*>(ws + (r - 144) * 768 + k);
    ushort4 h, l;
    h.x = f2bf(v.x); l.x = f2bf(v.x - bf2f(h.x));
    h.y = f2bf(v.y); l.y = f2bf(v.y - bf2f(h.y));
    h.z = f2bf(v.z); l.z = f2bf(v.z - bf2f(h.z));
    h.w = f2bf(v.w); l.w = f2bf(v.w - bf2f(h.w));
    *reinterpret_cast<ushort4*>(hi + i) = h;
    *reinterpret_cast<ushort4*>(lo + i) = l;
}

// ---------------------------------------------------------------------------
// bf16x3 split MFMA GEMM: out[M x Nt](fp32) = (Ahi+Alo)[M x K] @ (Bhi+Blo)^T
// via Ahi*Bhi + Ahi*Blo + Alo*Bhi.  B given row-major [Nt][K] (i.e. B^T form).
// 128x128 tile, 4 waves, each wave 64x64 (4x4 frags of 16x16), BK=32.
// M % 128 == 0, Nt % 128 == 0, K % 32 == 0 required.
// ---------------------------------------------------------------------------
#define BM 128
#define BN 128
#define BK 32

__device__ inline void gload16(const unsigned short* src, void* ldsbase) {
    __builtin_amdgcn_global_load_lds(
        (const __attribute__((address_space(1))) unsigned int*)src,
        (__attribute__((address_space(3))) unsigned int*)ldsbase, 16, 0, 0);
}

__global__ __launch_bounds__(256) void gemm_bf16x3(
    const unsigned short* __restrict__ Ahi, const unsigned short* __restrict__ Alo,
    const unsigned short* __restrict__ Bhi, const unsigned short* __restrict__ Blo,
    const float* __restrict__ bias,
    float* __restrict__ outp, int M, int Nt, int K)
{
    __shared__ unsigned short sAhi[BM][BK], sAlo[BM][BK];
    __shared__ unsigned short sBhi[BN][BK], sBlo[BN][BK];

    const int tid = threadIdx.x;
    const int w = tid >> 6, l = tid & 63;
    const int m0 = blockIdx.x * BM, n0 = blockIdx.y * BN;
    const int wr = (w >> 1) * 64, wc = (w & 1) * 64;   // wave's 64x64 sub-tile

    f32x4 acc[4][4];
    #pragma unroll
    for (int i = 0; i < 4; ++i)
        #pragma unroll
        for (int j = 0; j < 4; ++j)
            acc[i][j] = (f32x4){0.f, 0.f, 0.f, 0.f};

    // staging geometry: tile = 8192 B; wave w, issue i covers bytes
    // [i*4096 + w*1024, +1024); lane l -> +l*16. row = o>>6, col = (o&63)>>1.
    const int seg0 = w * 1024, seg1 = 4096 + w * 1024;
    const int o0 = seg0 + l * 16, o1 = seg1 + l * 16;
    const int r0 = o0 >> 6, c0 = (o0 & 63) >> 1;
    const int r1 = o1 >> 6, c1 = (o1 & 63) >> 1;

    const int lr = l & 15;          // row within 16x16 frag
    const int kb = (l >> 4) * 8;    // k offset (8 contiguous elems)

    for (int kk = 0; kk < K; kk += BK) {
        gload16(Ahi + (size_t)(m0 + r0) * K + kk + c0, (char*)sAhi + seg0);
        gload16(Ahi + (size_t)(m0 + r1) * K + kk + c1, (char*)sAhi + seg1);
        gload16(Alo + (size_t)(m0 + r0) * K + kk + c0, (char*)sAlo + seg0);
        gload16(Alo + (size_t)(m0 + r1) * K + kk + c1, (char*)sAlo + seg1);
        gload16(Bhi + (size_t)(n0 + r0) * K + kk + c0, (char*)sBhi + seg0);
        gload16(Bhi + (size_t)(n0 + r1) * K + kk + c1, (char*)sBhi + seg1);
        gload16(Blo + (size_t)(n0 + r0) * K + kk + c0, (char*)sBlo + seg0);
        gload16(Blo + (size_t)(n0 + r1) * K + kk + c1, (char*)sBlo + seg1);
        __syncthreads();   // compiler emits vmcnt(0) drain before barrier

        bf16x8 ah[4], al[4];
        #pragma unroll
        for (int fm = 0; fm < 4; ++fm) {
            ah[fm] = *reinterpret_cast<const bf16x8*>(&sAhi[wr + fm * 16 + lr][kb]);
            al[fm] = *reinterpret_cast<const bf16x8*>(&sAlo[wr + fm * 16 + lr][kb]);
        }
        #pragma unroll
        for (int fn = 0; fn < 4; ++fn) {
            bf16x8 bh = *reinterpret_cast<const bf16x8*>(&sBhi[wc + fn * 16 + lr][kb]);
            bf16x8 bl = *reinterpret_cast<const bf16x8*>(&sBlo[wc + fn * 16 + lr][kb]);
            #pragma unroll
            for (int fm = 0; fm < 4; ++fm) {
                acc[fm][fn] = __builtin_amdgcn_mfma_f32_16x16x32_bf16(ah[fm], bh, acc[fm][fn], 0, 0, 0);
                acc[fm][fn] = __builtin_amdgcn_mfma_f32_16x16x32_bf16(ah[fm], bl, acc[fm][fn], 0, 0, 0);
                acc[fm][fn] = __builtin_amdgcn_mfma_f32_16x16x32_bf16(al[fm], bh, acc[fm][fn], 0, 0, 0);
            }
        }
        __syncthreads();
    }

    // epilogue: C/D layout col=lane&15, row=(lane>>4)*4+reg  [m89-verified]
    const int rg = (l >> 4) * 4;
    #pragma unroll
    for (int fm = 0; fm < 4; ++fm) {
        #pragma unroll
        for (int fn = 0; fn < 4; ++fn) {
            const int row = m0 + wr + fm * 16 + rg;
            const int col = n0 + wc + fn * 16 + lr;
            const float bv = bias ? bias[col] : 0.f;
            #pragma unroll
            for (int r = 0; r < 4; ++r)
                outp[(size_t)(row + r) * Nt + col] = acc[fm][fn][r] + bv;
        }
    }
}

// ---------------------------------------------------------------------------
// Spatial attention: one block per (b,h,c); q,k,v are (196 x 16), fp32.
// qkv row stride NQKV_PAD; spatial cols = 144 + s*192 + h*16 + e.
// Output xs[((b*12+h)*196+n)*12 + c][16].
// ---------------------------------------------------------------------------
__global__ __launch_bounds__(256) void spatial_attn(
    const float* __restrict__ qkv,
    float* __restrict__ xs_out)
{
    const int bid = blockIdx.x;          // 8*12*12 = 1152
    const int c = bid % 12;
    const int h = (bid / 12) % 12;
    const int b = bid / 144;

    __shared__ float sQ[196][17];
    __shared__ float sK[196][17];
    __shared__ float sV[196][17];

    for (int idx = threadIdx.x; idx < N_ * 16; idx += 256) {
        const int n = idx >> 4, e = idx & 15;
        const float* base = qkv + (size_t)((b * N_ + n) * 12 + c) * NQKV_PAD + 144 + h * 16 + e;
        sQ[n][e] = base[0];
        sK[n][e] = base[192];
        sV[n][e] = base[384];
    }
    __syncthreads();

    const int n = threadIdx.x;
    if (n < N_) {
        float q[16];
        #pragma unroll
        for (int e = 0; e < 16; ++e) q[e] = sQ[n][e] * 0.25f;  // shd^-0.5

        float m = -INFINITY, lsum = 0.f;
        float acc[16] = {};
        for (int n2 = 0; n2 < N_; ++n2) {
            float s = 0.f;
            #pragma unroll
            for (int e = 0; e < 16; ++e) s += q[e] * sK[n2][e];
            const float mn = fmaxf(m, s);
            const float corr = __expf(m - mn);
            const float p = __expf(s - mn);
            lsum = lsum * corr + p;
            #pragma unroll
            for (int e = 0; e < 16; ++e) acc[e] = acc[e] * corr + p * sV[n2][e];
            m = mn;
        }
        const float inv = 1.f / lsum;
        const size_t orow = ((size_t)(b * 12 + h) * N_ + n) * 12 + c;
        #pragma unroll
        for (int e = 0; e < 16; ++e) xs_out[orow * 16 + e] = acc[e] * inv;
    }
}

// ---------------------------------------------------------------------------
// Channel attention (12x4 per (b,h,n)) + outer-product combine -> y (bf16 hi/lo)
// y[(b*196+n)*12 + h][c*64 + i*16 + j] = xc[c][i] * xs[c][j]
// ---------------------------------------------------------------------------
__global__ __launch_bounds__(64) void chan_attn_combine(
    const float* __restrict__ qkv,
    const float* __restrict__ xs,
    unsigned short* __restrict__ yhi,
    unsigned short* __restrict__ ylo)
{
    const int bid = blockIdx.x;            // ((b*12+h)*196 + n) ordering below
    const int n = bid % N_;
    const int h = (bid / N_) % 12;
    const int b = bid / (N_ * 12);
    const int t = threadIdx.x;

    __shared__ float sQ[12][4], sK[12][4], sV[12][4], sXc[12][4];
    __shared__ float sXs[12][16];

    for (int idx = t; idx < 144; idx += 64) {
        const int c = idx / 12, rem = idx % 12, s = rem >> 2, e = rem & 3;
        const float v = qkv[(size_t)((b * N_ + n) * 12 + c) * NQKV_PAD + s * 48 + h * 4 + e];
        if (s == 0) sQ[c][e] = v;
        else if (s == 1) sK[c][e] = v;
        else sV[c][e] = v;
    }
    for (int idx = t; idx < 192; idx += 64) {
        const int c = idx >> 4, j = idx & 15;
        sXs[c][j] = xs[(size_t)(((b * 12 + h) * N_ + n) * 12 + c) * 16 + j];
    }
    __syncthreads();

    if (t < 12) {
        const int c = t;
        float s[12];
        float m = -INFINITY;
        #pragma unroll
        for (int c2 = 0; c2 < 12; ++c2) {
            float d = 0.f;
            #pragma unroll
            for (int e = 0; e < 4; ++e) d += sQ[c][e] * sK[c2][e];
            s[c2] = d * 0.5f;                 // chd^-0.5
            m = fmaxf(m, s[c2]);
        }
        float lsum = 0.f;
        #pragma unroll
        for (int c2 = 0; c2 < 12; ++c2) { s[c2] = __expf(s[c2] - m); lsum += s[c2]; }
        const float inv = 1.f / lsum;
        #pragma unroll
        for (int i = 0; i < 4; ++i) {
            float a = 0.f;
            #pragma unroll
            for (int c2 = 0; c2 < 12; ++c2) a += s[c2] * sV[c2][i];
            sXc[c][i] = a * inv;
        }
    }
    __syncthreads();

    const size_t yrow = ((size_t)(b * N_ + n) * 12 + h) * (size_t)D_;
    #pragma unroll
    for (int k = 0; k < 12; ++k) {
        const float v = sXc[k][t >> 4] * sXs[k][t & 15];
        const unsigned short hv = f2bf(v);
        yhi[yrow + k * 64 + t] = hv;
        ylo[yrow + k * 64 + t] = f2bf(v - bf2f(hv));
    }
}

// ---------------------------------------------------------------------------
extern "C" void kernel_launch(void* const* d_in, const int* in_sizes, int n_in,
                              void* d_out, int out_size, void* d_ws, size_t ws_size,
                              hipStream_t stream) {
    const float* x       = (const float*)d_in[0];
    const float* w_qkv_c = (const float*)d_in[1];
    const float* w_qkv_s = (const float*)d_in[2];
    const float* w_proj  = (const float*)d_in[3];
    const float* b_proj  = (const float*)d_in[4];
    float* out = (float*)d_out;

    // Workspace layout (134.8 MB total):
    //   xhi/xlo : R_*768 bf16 each  (aliased as yhi/ylo after qkv GEMM)
    //   wqkv hi/lo, wproj hi/lo : 768*768 bf16 each
    //   qkv fp32 : R_*768 ; xs fp32 : B*H*N*C*16
    unsigned short* xhi = (unsigned short*)d_ws;
    unsigned short* xlo = xhi + (size_t)R_ * KDIM;
    unsigned short* wqkv_hi = xlo + (size_t)R_ * KDIM;
    unsigned short* wqkv_lo = wqkv_hi + (size_t)768 * 768;
    unsigned short* wp_hi   = wqkv_lo + (size_t)768 * 768;
    unsigned short* wp_lo   = wp_hi + (size_t)768 * 768;
    float* qkv = (float*)(wp_lo + (size_t)768 * 768);
    float* xs  = qkv + (size_t)R_ * NQKV_PAD;
    unsigned short* yhi = xhi;   // alias: x splits dead after qkv GEMM
    unsigned short* ylo = xlo;

    // 1) split-convert x and weights
    convert_split<<<(R_ * KDIM) / 1024, 256, 0, stream>>>(x, xhi, xlo, R_ * KDIM);
    convert_wqkv<<<(768 * 768) / 1024, 256, 0, stream>>>(w_qkv_c, w_qkv_s, wqkv_hi, wqkv_lo);
    convert_split<<<(768 * 768) / 1024, 256, 0, stream>>>(w_proj, wp_hi, wp_lo, 768 * 768);

    // 2) qkv GEMM (padded N=768)
    {
        dim3 grid(R_ / BM, NQKV_PAD / BN);
        gemm_bf16x3<<<grid, 256, 0, stream>>>(xhi, xlo, wqkv_hi, wqkv_lo, nullptr,
                                              qkv, R_, NQKV_PAD, KDIM);
    }
    // 3) spatial attention (fp32)
    spatial_attn<<<B_ * H_ * C_, 256, 0, stream>>>(qkv, xs);
    // 4) channel attention + combine -> y (bf16 hi/lo)
    chan_attn_combine<<<B_ * H_ * N_, 64, 0, stream>>>(qkv, xs, yhi, ylo);
    // 5) projection GEMM (+bias) -> d_out
    {
        dim3 grid(R_ / BM, D_ / BN);
        gemm_bf16x3<<<grid, 256, 0, stream>>>(yhi, ylo, wp_hi, wp_lo, b_proj,
                                              out, R_, D_, KDIM);
    }
}

// Round 3
// 292.408 us; speedup vs baseline: 2.6868x; 1.2140x over previous
//
#include <hip/hip_runtime.h>
#include <math.h>

// Problem constants
#define B_  8
#define N_  196
#define C_  12
#define D_  768
#define H_  12
#define R_  (B_*N_*C_)      // 18816 rows
#define KDIM 768
#define NQKV_PAD 768        // 720 real qkv cols padded to 768

typedef __attribute__((ext_vector_type(8))) short bf16x8;   // 8 bf16 = 4 VGPR
typedef __attribute__((ext_vector_type(4))) float f32x4;

__device__ inline unsigned short f2bf(float f) {
    union { float f; unsigned u; } v; v.f = f;
    unsigned r = v.u + 0x7fffu + ((v.u >> 16) & 1u);   // RNE
    return (unsigned short)(r >> 16);
}
__device__ inline float bf2f(unsigned short h) {
    union { unsigned u; float f; } v; v.u = ((unsigned)h) << 16; return v.f;
}

// ---------------------------------------------------------------------------
// fp32 -> (bf16 hi, bf16 lo) elementwise split. n must be a multiple of 4.
// ---------------------------------------------------------------------------
__global__ __launch_bounds__(256) void convert_split(
    const float* __restrict__ in, unsigned short* __restrict__ hi,
    unsigned short* __restrict__ lo, int n)
{
    int i = (blockIdx.x * 256 + threadIdx.x) * 4;
    if (i >= n) return;
    float4 v = *reinterpret_cast<const float4*>(in + i);
    ushort4 h, l;
    h.x = f2bf(v.x); l.x = f2bf(v.x - bf2f(h.x));
    h.y = f2bf(v.y); l.y = f2bf(v.y - bf2f(h.y));
    h.z = f2bf(v.z); l.z = f2bf(v.z - bf2f(h.z));
    h.w = f2bf(v.w); l.w = f2bf(v.w - bf2f(h.w));
    *reinterpret_cast<ushort4*>(hi + i) = h;
    *reinterpret_cast<ushort4*>(lo + i) = l;
}

// Pack w_qkv_c (144x768) + w_qkv_s (576x768) into padded 768x768 hi/lo.
__global__ __launch_bounds__(256) void convert_wqkv(
    const float* __restrict__ wc, const float* __restrict__ ws,
    unsigned short* __restrict__ hi, unsigned short* __restrict__ lo)
{
    int i = (blockIdx.x * 256 + threadIdx.x) * 4;
    if (i >= 768 * 768) return;
    int r = i / 768, k = i % 768;
    float4 v = make_float4(0.f, 0.f, 0.f, 0.f);
    if (r < 144)      v = *reinterpret_cast<const float4*>(wc + r * 768 + k);
    else if (r < 720) v = *reinterpret_cast<const float4*>(ws + (r - 144) * 768 + k);
    ushort4 h, l;
    h.x = f2bf(v.x); l.x = f2bf(v.x - bf2f(h.x));
    h.y = f2bf(v.y); l.y = f2bf(v.y - bf2f(h.y));
    h.z = f2bf(v.z); l.z = f2bf(v.z - bf2f(h.z));
    h.w = f2bf(v.w); l.w = f2bf(v.w - bf2f(h.w));
    *reinterpret_cast<ushort4*>(hi + i) = h;
    *reinterpret_cast<ushort4*>(lo + i) = l;
}

// ---------------------------------------------------------------------------
// bf16x3 split MFMA GEMM (unchanged from round 2, verified passing).
// ---------------------------------------------------------------------------
#define BM 128
#define BN 128
#define BK 32

__device__ inline void gload16(const unsigned short* src, void* ldsbase) {
    __builtin_amdgcn_global_load_lds(
        (const __attribute__((address_space(1))) unsigned int*)src,
        (__attribute__((address_space(3))) unsigned int*)ldsbase, 16, 0, 0);
}

__global__ __launch_bounds__(256) void gemm_bf16x3(
    const unsigned short* __restrict__ Ahi, const unsigned short* __restrict__ Alo,
    const unsigned short* __restrict__ Bhi, const unsigned short* __restrict__ Blo,
    const float* __restrict__ bias,
    float* __restrict__ outp, int M, int Nt, int K)
{
    __shared__ unsigned short sAhi[BM][BK], sAlo[BM][BK];
    __shared__ unsigned short sBhi[BN][BK], sBlo[BN][BK];

    const int tid = threadIdx.x;
    const int w = tid >> 6, l = tid & 63;
    const int m0 = blockIdx.x * BM, n0 = blockIdx.y * BN;
    const int wr = (w >> 1) * 64, wc = (w & 1) * 64;

    f32x4 acc[4][4];
    #pragma unroll
    for (int i = 0; i < 4; ++i)
        #pragma unroll
        for (int j = 0; j < 4; ++j)
            acc[i][j] = (f32x4){0.f, 0.f, 0.f, 0.f};

    const int seg0 = w * 1024, seg1 = 4096 + w * 1024;
    const int o0 = seg0 + l * 16, o1 = seg1 + l * 16;
    const int r0 = o0 >> 6, c0 = (o0 & 63) >> 1;
    const int r1 = o1 >> 6, c1 = (o1 & 63) >> 1;

    const int lr = l & 15;
    const int kb = (l >> 4) * 8;

    for (int kk = 0; kk < K; kk += BK) {
        gload16(Ahi + (size_t)(m0 + r0) * K + kk + c0, (char*)sAhi + seg0);
        gload16(Ahi + (size_t)(m0 + r1) * K + kk + c1, (char*)sAhi + seg1);
        gload16(Alo + (size_t)(m0 + r0) * K + kk + c0, (char*)sAlo + seg0);
        gload16(Alo + (size_t)(m0 + r1) * K + kk + c1, (char*)sAlo + seg1);
        gload16(Bhi + (size_t)(n0 + r0) * K + kk + c0, (char*)sBhi + seg0);
        gload16(Bhi + (size_t)(n0 + r1) * K + kk + c1, (char*)sBhi + seg1);
        gload16(Blo + (size_t)(n0 + r0) * K + kk + c0, (char*)sBlo + seg0);
        gload16(Blo + (size_t)(n0 + r1) * K + kk + c1, (char*)sBlo + seg1);
        __syncthreads();

        bf16x8 ah[4], al[4];
        #pragma unroll
        for (int fm = 0; fm < 4; ++fm) {
            ah[fm] = *reinterpret_cast<const bf16x8*>(&sAhi[wr + fm * 16 + lr][kb]);
            al[fm] = *reinterpret_cast<const bf16x8*>(&sAlo[wr + fm * 16 + lr][kb]);
        }
        #pragma unroll
        for (int fn = 0; fn < 4; ++fn) {
            bf16x8 bh = *reinterpret_cast<const bf16x8*>(&sBhi[wc + fn * 16 + lr][kb]);
            bf16x8 bl = *reinterpret_cast<const bf16x8*>(&sBlo[wc + fn * 16 + lr][kb]);
            #pragma unroll
            for (int fm = 0; fm < 4; ++fm) {
                acc[fm][fn] = __builtin_amdgcn_mfma_f32_16x16x32_bf16(ah[fm], bh, acc[fm][fn], 0, 0, 0);
                acc[fm][fn] = __builtin_amdgcn_mfma_f32_16x16x32_bf16(ah[fm], bl, acc[fm][fn], 0, 0, 0);
                acc[fm][fn] = __builtin_amdgcn_mfma_f32_16x16x32_bf16(al[fm], bh, acc[fm][fn], 0, 0, 0);
            }
        }
        __syncthreads();
    }

    const int rg = (l >> 4) * 4;
    #pragma unroll
    for (int fm = 0; fm < 4; ++fm) {
        #pragma unroll
        for (int fn = 0; fn < 4; ++fn) {
            const int row = m0 + wr + fm * 16 + rg;
            const int col = n0 + wc + fn * 16 + lr;
            const float bv = bias ? bias[col] : 0.f;
            #pragma unroll
            for (int r = 0; r < 4; ++r)
                outp[(size_t)(row + r) * Nt + col] = acc[fm][fn][r] + bv;
        }
    }
}

// ---------------------------------------------------------------------------
// MFMA spatial attention. One block per (b,h,c); 4 waves; each wave owns
// q-tiles {w, w+4, w+8, w+12} (13 tiles of 16 q-rows, 196 padded to 208).
// Flash-chunked over k (7 chunks of 32, 196 padded to 224).
//
// T = K·Q^T  (so q lives in lane&15 of the C-frag -> shuffle-cheap softmax)
//   MFMA1: A=[Khi|Klo], B=[Qhi|Qhi]  -> Khi·Qhi + Klo·Qhi
//   MFMA2: A=[Khi|Khi], B=[Qlo|0]    -> Khi·Qlo
// O^T = V^T·P^T (3 MFMAs: Vhi·Phi + Vlo·Phi + Vhi·Plo), P via wave-private
// LDS round-trip [16][72].
// Scale 1/sqrt(16) folded into Q at staging (exact, power of 2).
// ---------------------------------------------------------------------------
__global__ __launch_bounds__(256) void spatial_attn_mfma(
    const float* __restrict__ qkv,
    float* __restrict__ xs_out)
{
    __shared__ unsigned short Kl[224][32];     // [krow][ Khi(16) | Klo(16) ]
    __shared__ unsigned short Ql[208][40];     // [qrow][ Qhi(16) | Qlo(16) | pad ]
    __shared__ unsigned short VtH[16][224];    // V^T hi: [d][k]
    __shared__ unsigned short VtL[16][224];    // V^T lo
    __shared__ unsigned short Pb[4][16][72];   // per-wave: [q][ Phi(32) | Plo(32) | pad ]

    const int bid = blockIdx.x;                // 1152 = 8*12*12
    const int c = bid % 12;
    const int h = (bid / 12) % 12;
    const int b = bid / 144;
    const int tid = threadIdx.x;
    const int w = tid >> 6, l = tid & 63;
    const int fl = l & 15, g = l >> 4;

    // ---- stage Q,K,V (fp32 -> bf16 hi/lo, V transposed) ----
    for (int idx = tid; idx < N_ * 16; idx += 256) {
        const int n = idx >> 4, e = idx & 15;
        const float* base = qkv + (size_t)((b * N_ + n) * 12 + c) * NQKV_PAD + 144 + h * 16 + e;
        const float qv = base[0] * 0.25f;      // fold softmax scale into Q
        const float kv = base[192];
        const float vv = base[384];
        const unsigned short qh = f2bf(qv), kh = f2bf(kv), vh = f2bf(vv);
        Ql[n][e]      = qh;  Ql[n][16 + e] = f2bf(qv - bf2f(qh));
        Kl[n][e]      = kh;  Kl[n][16 + e] = f2bf(kv - bf2f(kh));
        VtH[e][n]     = vh;  VtL[e][n]     = f2bf(vv - bf2f(vh));
    }
    // zero V^T pad columns (0 * garbage = NaN hazard otherwise)
    for (int idx = tid; idx < 16 * 28; idx += 256) {
        const int d = idx / 28, n = 196 + idx % 28;
        VtH[d][n] = 0; VtL[d][n] = 0;
    }
    __syncthreads();

    f32x4 accO[4];
    float mrun[4], lsum[4];
    #pragma unroll
    for (int j = 0; j < 4; ++j) {
        accO[j] = (f32x4){0.f, 0.f, 0.f, 0.f};
        mrun[j] = -INFINITY; lsum[j] = 0.f;
    }
    const f32x4 zf = (f32x4){0.f, 0.f, 0.f, 0.f};
    const bf16x8 zb = (bf16x8){0, 0, 0, 0, 0, 0, 0, 0};

    for (int ch = 0; ch < 7; ++ch) {
        const int kb0 = ch * 32;
        // K fragments (shared across q-tiles)
        const bf16x8 A1a = *reinterpret_cast<const bf16x8*>(&Kl[kb0 + fl][8 * g]);
        const bf16x8 A1b = *reinterpret_cast<const bf16x8*>(&Kl[kb0 + 16 + fl][8 * g]);
        const bf16x8 A2a = *reinterpret_cast<const bf16x8*>(&Kl[kb0 + fl][8 * (g & 1)]);
        const bf16x8 A2b = *reinterpret_cast<const bf16x8*>(&Kl[kb0 + 16 + fl][8 * (g & 1)]);
        // V^T fragments
        const bf16x8 AvH = *reinterpret_cast<const bf16x8*>(&VtH[fl][kb0 + 8 * g]);
        const bf16x8 AvL = *reinterpret_cast<const bf16x8*>(&VtL[fl][kb0 + 8 * g]);

        #pragma unroll
        for (int j = 0; j < 4; ++j) {
            const int qt = w + 4 * j;
            if (qt > 12) continue;             // wave-uniform
            const int qrow = qt * 16 + fl;
            const bf16x8 Bq1 = *reinterpret_cast<const bf16x8*>(&Ql[qrow][8 * (g & 1)]);
            bf16x8 Bq2 = *reinterpret_cast<const bf16x8*>(&Ql[qrow][16 + 8 * (g & 1)]);
            if (g >= 2) Bq2 = zb;

            f32x4 T0 = zf, T1 = zf;
            T0 = __builtin_amdgcn_mfma_f32_16x16x32_bf16(A1a, Bq1, T0, 0, 0, 0);
            T0 = __builtin_amdgcn_mfma_f32_16x16x32_bf16(A2a, Bq2, T0, 0, 0, 0);
            T1 = __builtin_amdgcn_mfma_f32_16x16x32_bf16(A1b, Bq1, T1, 0, 0, 0);
            T1 = __builtin_amdgcn_mfma_f32_16x16x32_bf16(A2b, Bq2, T1, 0, 0, 0);

            float s0 = T0[0], s1 = T0[1], s2 = T0[2], s3 = T0[3];
            float s4 = T1[0], s5 = T1[1], s6 = T1[2], s7 = T1[3];
            if (ch == 6) {                      // mask pad k-rows (k >= 196)
                const int kg = kb0 + 4 * g;     // + 16*t + r
                if (kg + 0 >= 196) s0 = -1e30f;
                if (kg + 1 >= 196) s1 = -1e30f;
                if (kg + 2 >= 196) s2 = -1e30f;
                if (kg + 3 >= 196) s3 = -1e30f;
                s4 = -1e30f; s5 = -1e30f; s6 = -1e30f; s7 = -1e30f;  // k >= 208
            }
            float cm = fmaxf(fmaxf(fmaxf(s0, s1), fmaxf(s2, s3)),
                             fmaxf(fmaxf(s4, s5), fmaxf(s6, s7)));
            cm = fmaxf(cm, __shfl_xor(cm, 16));
            cm = fmaxf(cm, __shfl_xor(cm, 32));
            const float mn = fmaxf(mrun[j], cm);
            const float corr = __expf(mrun[j] - mn);
            mrun[j] = mn;
            const float p0 = __expf(s0 - mn), p1 = __expf(s1 - mn);
            const float p2 = __expf(s2 - mn), p3 = __expf(s3 - mn);
            const float p4 = __expf(s4 - mn), p5 = __expf(s5 - mn);
            const float p6 = __expf(s6 - mn), p7 = __expf(s7 - mn);
            float ps = ((p0 + p1) + (p2 + p3)) + ((p4 + p5) + (p6 + p7));
            ps += __shfl_xor(ps, 16);
            ps += __shfl_xor(ps, 32);
            lsum[j] = lsum[j] * corr + ps;
            accO[j][0] *= corr; accO[j][1] *= corr;
            accO[j][2] *= corr; accO[j][3] *= corr;

            // P -> bf16 hi/lo, through wave-private LDS
            unsigned short h0 = f2bf(p0), h1 = f2bf(p1), h2 = f2bf(p2), h3 = f2bf(p3);
            unsigned short h4 = f2bf(p4), h5 = f2bf(p5), h6 = f2bf(p6), h7 = f2bf(p7);
            uint2 whi0, whi1, wlo0, wlo1;
            whi0.x = (unsigned)h0 | ((unsigned)h1 << 16);
            whi0.y = (unsigned)h2 | ((unsigned)h3 << 16);
            whi1.x = (unsigned)h4 | ((unsigned)h5 << 16);
            whi1.y = (unsigned)h6 | ((unsigned)h7 << 16);
            wlo0.x = (unsigned)f2bf(p0 - bf2f(h0)) | ((unsigned)f2bf(p1 - bf2f(h1)) << 16);
            wlo0.y = (unsigned)f2bf(p2 - bf2f(h2)) | ((unsigned)f2bf(p3 - bf2f(h3)) << 16);
            wlo1.x = (unsigned)f2bf(p4 - bf2f(h4)) | ((unsigned)f2bf(p5 - bf2f(h5)) << 16);
            wlo1.y = (unsigned)f2bf(p6 - bf2f(h6)) | ((unsigned)f2bf(p7 - bf2f(h7)) << 16);
            *reinterpret_cast<uint2*>(&Pb[w][fl][4 * g])      = whi0;   // k = 4g..,   t'=0
            *reinterpret_cast<uint2*>(&Pb[w][fl][16 + 4 * g]) = whi1;   // t'=1
            *reinterpret_cast<uint2*>(&Pb[w][fl][32 + 4 * g])      = wlo0;
            *reinterpret_cast<uint2*>(&Pb[w][fl][48 + 4 * g])      = wlo1;

            const bf16x8 BpH = *reinterpret_cast<const bf16x8*>(&Pb[w][fl][8 * g]);
            const bf16x8 BpL = *reinterpret_cast<const bf16x8*>(&Pb[w][fl][32 + 8 * g]);
            accO[j] = __builtin_amdgcn_mfma_f32_16x16x32_bf16(AvH, BpH, accO[j], 0, 0, 0);
            accO[j] = __builtin_amdgcn_mfma_f32_16x16x32_bf16(AvL, BpH, accO[j], 0, 0, 0);
            accO[j] = __builtin_amdgcn_mfma_f32_16x16x32_bf16(AvH, BpL, accO[j], 0, 0, 0);
        }
    }

    // ---- normalize + store: O^T C-frag col=fl=q, rows d=4g+r ----
    #pragma unroll
    for (int j = 0; j < 4; ++j) {
        const int qt = w + 4 * j;
        if (qt > 12) continue;
        const int n = qt * 16 + fl;
        if (n < 196) {
            const float inv = 1.f / lsum[j];
            float4 o;
            o.x = accO[j][0] * inv; o.y = accO[j][1] * inv;
            o.z = accO[j][2] * inv; o.w = accO[j][3] * inv;
            const size_t base = ((size_t)((b * 12 + h) * N_ + n) * 12 + c) * 16 + 4 * g;
            *reinterpret_cast<float4*>(&xs_out[base]) = o;
        }
    }
}

// ---------------------------------------------------------------------------
// Channel attention (12x4 per (b,h,n)) + outer-product combine -> y (bf16 hi/lo)
// ---------------------------------------------------------------------------
__global__ __launch_bounds__(64) void chan_attn_combine(
    const float* __restrict__ qkv,
    const float* __restrict__ xs,
    unsigned short* __restrict__ yhi,
    unsigned short* __restrict__ ylo)
{
    const int bid = blockIdx.x;
    const int n = bid % N_;
    const int h = (bid / N_) % 12;
    const int b = bid / (N_ * 12);
    const int t = threadIdx.x;

    __shared__ float sQ[12][4], sK[12][4], sV[12][4], sXc[12][4];
    __shared__ float sXs[12][16];

    for (int idx = t; idx < 144; idx += 64) {
        const int c = idx / 12, rem = idx % 12, s = rem >> 2, e = rem & 3;
        const float v = qkv[(size_t)((b * N_ + n) * 12 + c) * NQKV_PAD + s * 48 + h * 4 + e];
        if (s == 0) sQ[c][e] = v;
        else if (s == 1) sK[c][e] = v;
        else sV[c][e] = v;
    }
    for (int idx = t; idx < 192; idx += 64) {
        const int c = idx >> 4, j = idx & 15;
        sXs[c][j] = xs[(size_t)(((b * 12 + h) * N_ + n) * 12 + c) * 16 + j];
    }
    __syncthreads();

    if (t < 12) {
        const int c = t;
        float s[12];
        float m = -INFINITY;
        #pragma unroll
        for (int c2 = 0; c2 < 12; ++c2) {
            float d = 0.f;
            #pragma unroll
            for (int e = 0; e < 4; ++e) d += sQ[c][e] * sK[c2][e];
            s[c2] = d * 0.5f;
            m = fmaxf(m, s[c2]);
        }
        float lsum = 0.f;
        #pragma unroll
        for (int c2 = 0; c2 < 12; ++c2) { s[c2] = __expf(s[c2] - m); lsum += s[c2]; }
        const float inv = 1.f / lsum;
        #pragma unroll
        for (int i = 0; i < 4; ++i) {
            float a = 0.f;
            #pragma unroll
            for (int c2 = 0; c2 < 12; ++c2) a += s[c2] * sV[c2][i];
            sXc[c][i] = a * inv;
        }
    }
    __syncthreads();

    const size_t yrow = ((size_t)(b * N_ + n) * 12 + h) * (size_t)D_;
    #pragma unroll
    for (int k = 0; k < 12; ++k) {
        const float v = sXc[k][t >> 4] * sXs[k][t & 15];
        const unsigned short hv = f2bf(v);
        yhi[yrow + k * 64 + t] = hv;
        ylo[yrow + k * 64 + t] = f2bf(v - bf2f(hv));
    }
}

// ---------------------------------------------------------------------------
extern "C" void kernel_launch(void* const* d_in, const int* in_sizes, int n_in,
                              void* d_out, int out_size, void* d_ws, size_t ws_size,
                              hipStream_t stream) {
    const float* x       = (const float*)d_in[0];
    const float* w_qkv_c = (const float*)d_in[1];
    const float* w_qkv_s = (const float*)d_in[2];
    const float* w_proj  = (const float*)d_in[3];
    const float* b_proj  = (const float*)d_in[4];
    float* out = (float*)d_out;

    unsigned short* xhi = (unsigned short*)d_ws;
    unsigned short* xlo = xhi + (size_t)R_ * KDIM;
    unsigned short* wqkv_hi = xlo + (size_t)R_ * KDIM;
    unsigned short* wqkv_lo = wqkv_hi + (size_t)768 * 768;
    unsigned short* wp_hi   = wqkv_lo + (size_t)768 * 768;
    unsigned short* wp_lo   = wp_hi + (size_t)768 * 768;
    float* qkv = (float*)(wp_lo + (size_t)768 * 768);
    float* xs  = qkv + (size_t)R_ * NQKV_PAD;
    unsigned short* yhi = xhi;   // alias: x splits dead after qkv GEMM
    unsigned short* ylo = xlo;

    convert_split<<<(R_ * KDIM) / 1024, 256, 0, stream>>>(x, xhi, xlo, R_ * KDIM);
    convert_wqkv<<<(768 * 768) / 1024, 256, 0, stream>>>(w_qkv_c, w_qkv_s, wqkv_hi, wqkv_lo);
    convert_split<<<(768 * 768) / 1024, 256, 0, stream>>>(w_proj, wp_hi, wp_lo, 768 * 768);

    {
        dim3 grid(R_ / BM, NQKV_PAD / BN);
        gemm_bf16x3<<<grid, 256, 0, stream>>>(xhi, xlo, wqkv_hi, wqkv_lo, nullptr,
                                              qkv, R_, NQKV_PAD, KDIM);
    }
    spatial_attn_mfma<<<B_ * H_ * C_, 256, 0, stream>>>(qkv, xs);
    chan_attn_combine<<<B_ * H_ * N_, 64, 0, stream>>>(qkv, xs, yhi, ylo);
    {
        dim3 grid(R_ / BM, D_ / BN);
        gemm_bf16x3<<<grid, 256, 0, stream>>>(yhi, ylo, wp_hi, wp_lo, b_proj,
                                              out, R_, D_, KDIM);
    }
}

// Round 4
// 260.882 us; speedup vs baseline: 3.0114x; 1.1208x over previous
//
#include <hip/hip_runtime.h>
#include <math.h>

// Problem constants
#define B_  8
#define N_  196
#define C_  12
#define D_  768
#define H_  12
#define R_  (B_*N_*C_)      // 18816 rows
#define KDIM 768
#define NQKV_PAD 768        // 720 real qkv cols padded to 768

typedef __attribute__((ext_vector_type(8))) short bf16x8;   // 8 bf16 = 4 VGPR
typedef __attribute__((ext_vector_type(4))) float f32x4;

__device__ inline unsigned short f2bf(float f) {
    union { float f; unsigned u; } v; v.f = f;
    unsigned r = v.u + 0x7fffu + ((v.u >> 16) & 1u);   // RNE
    return (unsigned short)(r >> 16);
}
__device__ inline float bf2f(unsigned short h) {
    union { unsigned u; float f; } v; v.u = ((unsigned)h) << 16; return v.f;
}

// ---------------------------------------------------------------------------
// fp32 -> (bf16 hi, bf16 lo) elementwise split. n must be a multiple of 4.
// ---------------------------------------------------------------------------
__global__ __launch_bounds__(256) void convert_split(
    const float* __restrict__ in, unsigned short* __restrict__ hi,
    unsigned short* __restrict__ lo, int n)
{
    int i = (blockIdx.x * 256 + threadIdx.x) * 4;
    if (i >= n) return;
    float4 v = *reinterpret_cast<const float4*>(in + i);
    ushort4 h, l;
    h.x = f2bf(v.x); l.x = f2bf(v.x - bf2f(h.x));
    h.y = f2bf(v.y); l.y = f2bf(v.y - bf2f(h.y));
    h.z = f2bf(v.z); l.z = f2bf(v.z - bf2f(h.z));
    h.w = f2bf(v.w); l.w = f2bf(v.w - bf2f(h.w));
    *reinterpret_cast<ushort4*>(hi + i) = h;
    *reinterpret_cast<ushort4*>(lo + i) = l;
}

// Pack w_qkv_c (144x768) + w_qkv_s (576x768) into padded 768x768 hi/lo.
__global__ __launch_bounds__(256) void convert_wqkv(
    const float* __restrict__ wc, const float* __restrict__ ws,
    unsigned short* __restrict__ hi, unsigned short* __restrict__ lo)
{
    int i = (blockIdx.x * 256 + threadIdx.x) * 4;
    if (i >= 768 * 768) return;
    int r = i / 768, k = i % 768;
    float4 v = make_float4(0.f, 0.f, 0.f, 0.f);
    if (r < 144)      v = *reinterpret_cast<const float4*>(wc + r * 768 + k);
    else if (r < 720) v = *reinterpret_cast<const float4*>(ws + (r - 144) * 768 + k);
    ushort4 h, l;
    h.x = f2bf(v.x); l.x = f2bf(v.x - bf2f(h.x));
    h.y = f2bf(v.y); l.y = f2bf(v.y - bf2f(h.y));
    h.z = f2bf(v.z); l.z = f2bf(v.z - bf2f(h.z));
    h.w = f2bf(v.w); l.w = f2bf(v.w - bf2f(h.w));
    *reinterpret_cast<ushort4*>(hi + i) = h;
    *reinterpret_cast<ushort4*>(lo + i) = l;
}

// ---------------------------------------------------------------------------
// bf16x3 split MFMA GEMM, 2-phase double-buffered + chunked XCD swizzle.
// out[M x Nt](fp32) = (Ahi+Alo)[M x K] @ (Bhi+Blo)^T via 3 MFMA terms.
// 128x128 tile, 4 waves x 64x64, BK=32, 1-D grid (mtiles*ntiles), nt-fast
// decomposition so blocks sharing an A-panel are XCD-contiguous.
// ---------------------------------------------------------------------------
#define BM 128
#define BN 128
#define BK 32

__device__ inline void gload16(const unsigned short* src, void* ldsbase) {
    __builtin_amdgcn_global_load_lds(
        (const __attribute__((address_space(1))) unsigned int*)src,
        (__attribute__((address_space(3))) unsigned int*)ldsbase, 16, 0, 0);
}

__global__ __launch_bounds__(256) void gemm_bf16x3(
    const unsigned short* __restrict__ Ahi, const unsigned short* __restrict__ Alo,
    const unsigned short* __restrict__ Bhi, const unsigned short* __restrict__ Blo,
    const float* __restrict__ bias,
    float* __restrict__ outp, int M, int Nt, int K, int ntiles)
{
    __shared__ unsigned short sAhi[2][BM][BK], sAlo[2][BM][BK];
    __shared__ unsigned short sBhi[2][BN][BK], sBlo[2][BN][BK];

    // chunked bijective XCD swizzle (m204): contiguous logical range per XCD
    const int nwg = gridDim.x;
    const int bid = blockIdx.x;
    const int xcd = bid & 7, slot = bid >> 3;
    const int q = nwg >> 3, r = nwg & 7;
    const int wg = (xcd < r ? xcd * (q + 1) : r * (q + 1) + (xcd - r) * q) + slot;
    const int mt = wg / ntiles, nt = wg - mt * ntiles;   // nt fast: A-panel reuse
    const int m0 = mt * BM, n0 = nt * BN;

    const int tid = threadIdx.x;
    const int w = tid >> 6, l = tid & 63;
    const int wr = (w >> 1) * 64, wc = (w & 1) * 64;

    f32x4 acc[4][4];
    #pragma unroll
    for (int i = 0; i < 4; ++i)
        #pragma unroll
        for (int j = 0; j < 4; ++j)
            acc[i][j] = (f32x4){0.f, 0.f, 0.f, 0.f};

    // staging geometry: one 8KB tile per array per buffer; wave w covers
    // bytes [w*1024,+1024) and [4096+w*1024,+1024); lane adds l*16.
    const int seg0 = w * 1024, seg1 = 4096 + w * 1024;
    const int o0 = seg0 + l * 16, o1 = seg1 + l * 16;
    const int r0 = o0 >> 6, c0 = (o0 & 63) >> 1;
    const int r1 = o1 >> 6, c1 = (o1 & 63) >> 1;

    const int lr = l & 15;
    const int kb = (l >> 4) * 8;

#define STAGE(buf, kk)                                                                     \
    gload16(Ahi + (size_t)(m0 + r0) * K + (kk) + c0, (char*)sAhi + (buf) * 8192 + seg0);   \
    gload16(Ahi + (size_t)(m0 + r1) * K + (kk) + c1, (char*)sAhi + (buf) * 8192 + seg1);   \
    gload16(Alo + (size_t)(m0 + r0) * K + (kk) + c0, (char*)sAlo + (buf) * 8192 + seg0);   \
    gload16(Alo + (size_t)(m0 + r1) * K + (kk) + c1, (char*)sAlo + (buf) * 8192 + seg1);   \
    gload16(Bhi + (size_t)(n0 + r0) * K + (kk) + c0, (char*)sBhi + (buf) * 8192 + seg0);   \
    gload16(Bhi + (size_t)(n0 + r1) * K + (kk) + c1, (char*)sBhi + (buf) * 8192 + seg1);   \
    gload16(Blo + (size_t)(n0 + r0) * K + (kk) + c0, (char*)sBlo + (buf) * 8192 + seg0);   \
    gload16(Blo + (size_t)(n0 + r1) * K + (kk) + c1, (char*)sBlo + (buf) * 8192 + seg1);

    STAGE(0, 0);
    __syncthreads();

    const int KT = K / BK;
    int cur = 0;
    for (int t = 0; t < KT; ++t) {
        if (t + 1 < KT) { STAGE(cur ^ 1, (t + 1) * BK); }   // loads fly over MFMAs

        bf16x8 ah[4], al[4];
        #pragma unroll
        for (int fm = 0; fm < 4; ++fm) {
            ah[fm] = *reinterpret_cast<const bf16x8*>(&sAhi[cur][wr + fm * 16 + lr][kb]);
            al[fm] = *reinterpret_cast<const bf16x8*>(&sAlo[cur][wr + fm * 16 + lr][kb]);
        }
        #pragma unroll
        for (int fn = 0; fn < 4; ++fn) {
            bf16x8 bh = *reinterpret_cast<const bf16x8*>(&sBhi[cur][wc + fn * 16 + lr][kb]);
            bf16x8 bl = *reinterpret_cast<const bf16x8*>(&sBlo[cur][wc + fn * 16 + lr][kb]);
            #pragma unroll
            for (int fm = 0; fm < 4; ++fm) {
                acc[fm][fn] = __builtin_amdgcn_mfma_f32_16x16x32_bf16(ah[fm], bh, acc[fm][fn], 0, 0, 0);
                acc[fm][fn] = __builtin_amdgcn_mfma_f32_16x16x32_bf16(ah[fm], bl, acc[fm][fn], 0, 0, 0);
                acc[fm][fn] = __builtin_amdgcn_mfma_f32_16x16x32_bf16(al[fm], bh, acc[fm][fn], 0, 0, 0);
            }
        }
        __syncthreads();   // drains vmcnt(0)+lgkmcnt(0): next buffer ready
        cur ^= 1;
    }
#undef STAGE

    const int rg = (l >> 4) * 4;
    #pragma unroll
    for (int fm = 0; fm < 4; ++fm) {
        #pragma unroll
        for (int fn = 0; fn < 4; ++fn) {
            const int row = m0 + wr + fm * 16 + rg;
            const int col = n0 + wc + fn * 16 + lr;
            const float bv = bias ? bias[col] : 0.f;
            #pragma unroll
            for (int rr = 0; rr < 4; ++rr)
                outp[(size_t)(row + rr) * Nt + col] = acc[fm][fn][rr] + bv;
        }
    }
}

// ---------------------------------------------------------------------------
// MFMA spatial attention (unchanged from round 3, verified passing).
// ---------------------------------------------------------------------------
__global__ __launch_bounds__(256) void spatial_attn_mfma(
    const float* __restrict__ qkv,
    float* __restrict__ xs_out)
{
    __shared__ unsigned short Kl[224][32];
    __shared__ unsigned short Ql[208][40];
    __shared__ unsigned short VtH[16][224];
    __shared__ unsigned short VtL[16][224];
    __shared__ unsigned short Pb[4][16][72];

    const int bid = blockIdx.x;                // 1152 = 8*12*12
    const int c = bid % 12;
    const int h = (bid / 12) % 12;
    const int b = bid / 144;
    const int tid = threadIdx.x;
    const int w = tid >> 6, l = tid & 63;
    const int fl = l & 15, g = l >> 4;

    for (int idx = tid; idx < N_ * 16; idx += 256) {
        const int n = idx >> 4, e = idx & 15;
        const float* base = qkv + (size_t)((b * N_ + n) * 12 + c) * NQKV_PAD + 144 + h * 16 + e;
        const float qv = base[0] * 0.25f;
        const float kv = base[192];
        const float vv = base[384];
        const unsigned short qh = f2bf(qv), kh = f2bf(kv), vh = f2bf(vv);
        Ql[n][e]      = qh;  Ql[n][16 + e] = f2bf(qv - bf2f(qh));
        Kl[n][e]      = kh;  Kl[n][16 + e] = f2bf(kv - bf2f(kh));
        VtH[e][n]     = vh;  VtL[e][n]     = f2bf(vv - bf2f(vh));
    }
    for (int idx = tid; idx < 16 * 28; idx += 256) {
        const int d = idx / 28, n = 196 + idx % 28;
        VtH[d][n] = 0; VtL[d][n] = 0;
    }
    __syncthreads();

    f32x4 accO[4];
    float mrun[4], lsum[4];
    #pragma unroll
    for (int j = 0; j < 4; ++j) {
        accO[j] = (f32x4){0.f, 0.f, 0.f, 0.f};
        mrun[j] = -INFINITY; lsum[j] = 0.f;
    }
    const f32x4 zf = (f32x4){0.f, 0.f, 0.f, 0.f};
    const bf16x8 zb = (bf16x8){0, 0, 0, 0, 0, 0, 0, 0};

    for (int ch = 0; ch < 7; ++ch) {
        const int kb0 = ch * 32;
        const bf16x8 A1a = *reinterpret_cast<const bf16x8*>(&Kl[kb0 + fl][8 * g]);
        const bf16x8 A1b = *reinterpret_cast<const bf16x8*>(&Kl[kb0 + 16 + fl][8 * g]);
        const bf16x8 A2a = *reinterpret_cast<const bf16x8*>(&Kl[kb0 + fl][8 * (g & 1)]);
        const bf16x8 A2b = *reinterpret_cast<const bf16x8*>(&Kl[kb0 + 16 + fl][8 * (g & 1)]);
        const bf16x8 AvH = *reinterpret_cast<const bf16x8*>(&VtH[fl][kb0 + 8 * g]);
        const bf16x8 AvL = *reinterpret_cast<const bf16x8*>(&VtL[fl][kb0 + 8 * g]);

        #pragma unroll
        for (int j = 0; j < 4; ++j) {
            const int qt = w + 4 * j;
            if (qt > 12) continue;
            const int qrow = qt * 16 + fl;
            const bf16x8 Bq1 = *reinterpret_cast<const bf16x8*>(&Ql[qrow][8 * (g & 1)]);
            bf16x8 Bq2 = *reinterpret_cast<const bf16x8*>(&Ql[qrow][16 + 8 * (g & 1)]);
            if (g >= 2) Bq2 = zb;

            f32x4 T0 = zf, T1 = zf;
            T0 = __builtin_amdgcn_mfma_f32_16x16x32_bf16(A1a, Bq1, T0, 0, 0, 0);
            T0 = __builtin_amdgcn_mfma_f32_16x16x32_bf16(A2a, Bq2, T0, 0, 0, 0);
            T1 = __builtin_amdgcn_mfma_f32_16x16x32_bf16(A1b, Bq1, T1, 0, 0, 0);
            T1 = __builtin_amdgcn_mfma_f32_16x16x32_bf16(A2b, Bq2, T1, 0, 0, 0);

            float s0 = T0[0], s1 = T0[1], s2 = T0[2], s3 = T0[3];
            float s4 = T1[0], s5 = T1[1], s6 = T1[2], s7 = T1[3];
            if (ch == 6) {
                const int kg = kb0 + 4 * g;
                if (kg + 0 >= 196) s0 = -1e30f;
                if (kg + 1 >= 196) s1 = -1e30f;
                if (kg + 2 >= 196) s2 = -1e30f;
                if (kg + 3 >= 196) s3 = -1e30f;
                s4 = -1e30f; s5 = -1e30f; s6 = -1e30f; s7 = -1e30f;
            }
            float cm = fmaxf(fmaxf(fmaxf(s0, s1), fmaxf(s2, s3)),
                             fmaxf(fmaxf(s4, s5), fmaxf(s6, s7)));
            cm = fmaxf(cm, __shfl_xor(cm, 16));
            cm = fmaxf(cm, __shfl_xor(cm, 32));
            const float mn = fmaxf(mrun[j], cm);
            const float corr = __expf(mrun[j] - mn);
            mrun[j] = mn;
            const float p0 = __expf(s0 - mn), p1 = __expf(s1 - mn);
            const float p2 = __expf(s2 - mn), p3 = __expf(s3 - mn);
            const float p4 = __expf(s4 - mn), p5 = __expf(s5 - mn);
            const float p6 = __expf(s6 - mn), p7 = __expf(s7 - mn);
            float ps = ((p0 + p1) + (p2 + p3)) + ((p4 + p5) + (p6 + p7));
            ps += __shfl_xor(ps, 16);
            ps += __shfl_xor(ps, 32);
            lsum[j] = lsum[j] * corr + ps;
            accO[j][0] *= corr; accO[j][1] *= corr;
            accO[j][2] *= corr; accO[j][3] *= corr;

            unsigned short h0 = f2bf(p0), h1 = f2bf(p1), h2 = f2bf(p2), h3 = f2bf(p3);
            unsigned short h4 = f2bf(p4), h5 = f2bf(p5), h6 = f2bf(p6), h7 = f2bf(p7);
            uint2 whi0, whi1, wlo0, wlo1;
            whi0.x = (unsigned)h0 | ((unsigned)h1 << 16);
            whi0.y = (unsigned)h2 | ((unsigned)h3 << 16);
            whi1.x = (unsigned)h4 | ((unsigned)h5 << 16);
            whi1.y = (unsigned)h6 | ((unsigned)h7 << 16);
            wlo0.x = (unsigned)f2bf(p0 - bf2f(h0)) | ((unsigned)f2bf(p1 - bf2f(h1)) << 16);
            wlo0.y = (unsigned)f2bf(p2 - bf2f(h2)) | ((unsigned)f2bf(p3 - bf2f(h3)) << 16);
            wlo1.x = (unsigned)f2bf(p4 - bf2f(h4)) | ((unsigned)f2bf(p5 - bf2f(h5)) << 16);
            wlo1.y = (unsigned)f2bf(p6 - bf2f(h6)) | ((unsigned)f2bf(p7 - bf2f(h7)) << 16);
            *reinterpret_cast<uint2*>(&Pb[w][fl][4 * g])      = whi0;
            *reinterpret_cast<uint2*>(&Pb[w][fl][16 + 4 * g]) = whi1;
            *reinterpret_cast<uint2*>(&Pb[w][fl][32 + 4 * g]) = wlo0;
            *reinterpret_cast<uint2*>(&Pb[w][fl][48 + 4 * g]) = wlo1;

            const bf16x8 BpH = *reinterpret_cast<const bf16x8*>(&Pb[w][fl][8 * g]);
            const bf16x8 BpL = *reinterpret_cast<const bf16x8*>(&Pb[w][fl][32 + 8 * g]);
            accO[j] = __builtin_amdgcn_mfma_f32_16x16x32_bf16(AvH, BpH, accO[j], 0, 0, 0);
            accO[j] = __builtin_amdgcn_mfma_f32_16x16x32_bf16(AvL, BpH, accO[j], 0, 0, 0);
            accO[j] = __builtin_amdgcn_mfma_f32_16x16x32_bf16(AvH, BpL, accO[j], 0, 0, 0);
        }
    }

    #pragma unroll
    for (int j = 0; j < 4; ++j) {
        const int qt = w + 4 * j;
        if (qt > 12) continue;
        const int n = qt * 16 + fl;
        if (n < 196) {
            const float inv = 1.f / lsum[j];
            float4 o;
            o.x = accO[j][0] * inv; o.y = accO[j][1] * inv;
            o.z = accO[j][2] * inv; o.w = accO[j][3] * inv;
            const size_t base = ((size_t)((b * 12 + h) * N_ + n) * 12 + c) * 16 + 4 * g;
            *reinterpret_cast<float4*>(&xs_out[base]) = o;
        }
    }
}

// ---------------------------------------------------------------------------
// Channel attention (12x4 per (b,h,n)) + outer-product combine -> y (bf16 hi/lo)
// ---------------------------------------------------------------------------
__global__ __launch_bounds__(64) void chan_attn_combine(
    const float* __restrict__ qkv,
    const float* __restrict__ xs,
    unsigned short* __restrict__ yhi,
    unsigned short* __restrict__ ylo)
{
    const int bid = blockIdx.x;
    const int n = bid % N_;
    const int h = (bid / N_) % 12;
    const int b = bid / (N_ * 12);
    const int t = threadIdx.x;

    __shared__ float sQ[12][4], sK[12][4], sV[12][4], sXc[12][4];
    __shared__ float sXs[12][16];

    for (int idx = t; idx < 144; idx += 64) {
        const int c = idx / 12, rem = idx % 12, s = rem >> 2, e = rem & 3;
        const float v = qkv[(size_t)((b * N_ + n) * 12 + c) * NQKV_PAD + s * 48 + h * 4 + e];
        if (s == 0) sQ[c][e] = v;
        else if (s == 1) sK[c][e] = v;
        else sV[c][e] = v;
    }
    for (int idx = t; idx < 192; idx += 64) {
        const int c = idx >> 4, j = idx & 15;
        sXs[c][j] = xs[(size_t)(((b * 12 + h) * N_ + n) * 12 + c) * 16 + j];
    }
    __syncthreads();

    if (t < 12) {
        const int c = t;
        float s[12];
        float m = -INFINITY;
        #pragma unroll
        for (int c2 = 0; c2 < 12; ++c2) {
            float d = 0.f;
            #pragma unroll
            for (int e = 0; e < 4; ++e) d += sQ[c][e] * sK[c2][e];
            s[c2] = d * 0.5f;
            m = fmaxf(m, s[c2]);
        }
        float lsum = 0.f;
        #pragma unroll
        for (int c2 = 0; c2 < 12; ++c2) { s[c2] = __expf(s[c2] - m); lsum += s[c2]; }
        const float inv = 1.f / lsum;
        #pragma unroll
        for (int i = 0; i < 4; ++i) {
            float a = 0.f;
            #pragma unroll
            for (int c2 = 0; c2 < 12; ++c2) a += s[c2] * sV[c2][i];
            sXc[c][i] = a * inv;
        }
    }
    __syncthreads();

    const size_t yrow = ((size_t)(b * N_ + n) * 12 + h) * (size_t)D_;
    #pragma unroll
    for (int k = 0; k < 12; ++k) {
        const float v = sXc[k][t >> 4] * sXs[k][t & 15];
        const unsigned short hv = f2bf(v);
        yhi[yrow + k * 64 + t] = hv;
        ylo[yrow + k * 64 + t] = f2bf(v - bf2f(hv));
    }
}

// ---------------------------------------------------------------------------
extern "C" void kernel_launch(void* const* d_in, const int* in_sizes, int n_in,
                              void* d_out, int out_size, void* d_ws, size_t ws_size,
                              hipStream_t stream) {
    const float* x       = (const float*)d_in[0];
    const float* w_qkv_c = (const float*)d_in[1];
    const float* w_qkv_s = (const float*)d_in[2];
    const float* w_proj  = (const float*)d_in[3];
    const float* b_proj  = (const float*)d_in[4];
    float* out = (float*)d_out;

    unsigned short* xhi = (unsigned short*)d_ws;
    unsigned short* xlo = xhi + (size_t)R_ * KDIM;
    unsigned short* wqkv_hi = xlo + (size_t)R_ * KDIM;
    unsigned short* wqkv_lo = wqkv_hi + (size_t)768 * 768;
    unsigned short* wp_hi   = wqkv_lo + (size_t)768 * 768;
    unsigned short* wp_lo   = wp_hi + (size_t)768 * 768;
    float* qkv = (float*)(wp_lo + (size_t)768 * 768);
    float* xs  = qkv + (size_t)R_ * NQKV_PAD;
    unsigned short* yhi = xhi;   // alias: x splits dead after qkv GEMM
    unsigned short* ylo = xlo;

    convert_split<<<(R_ * KDIM) / 1024, 256, 0, stream>>>(x, xhi, xlo, R_ * KDIM);
    convert_wqkv<<<(768 * 768) / 1024, 256, 0, stream>>>(w_qkv_c, w_qkv_s, wqkv_hi, wqkv_lo);
    convert_split<<<(768 * 768) / 1024, 256, 0, stream>>>(w_proj, wp_hi, wp_lo, 768 * 768);

    {
        const int mtiles = R_ / BM, ntiles = NQKV_PAD / BN;
        gemm_bf16x3<<<mtiles * ntiles, 256, 0, stream>>>(
            xhi, xlo, wqkv_hi, wqkv_lo, nullptr, qkv, R_, NQKV_PAD, KDIM, ntiles);
    }
    spatial_attn_mfma<<<B_ * H_ * C_, 256, 0, stream>>>(qkv, xs);
    chan_attn_combine<<<B_ * H_ * N_, 64, 0, stream>>>(qkv, xs, yhi, ylo);
    {
        const int mtiles = R_ / BM, ntiles = D_ / BN;
        gemm_bf16x3<<<mtiles * ntiles, 256, 0, stream>>>(
            yhi, ylo, wp_hi, wp_lo, b_proj, out, R_, D_, KDIM, ntiles);
    }
}